// Round 1
// baseline (1472.506 us; speedup 1.0000x reference)
//
#include <hip/hip_runtime.h>
#include <math.h>

// ---------------------------------------------------------------------------
// HW_Block_Parallel: full forward pipeline on MI355X (fp32).
// Stages: stats -> att -> prep(NHWC x_channels/x_concat) -> dwconv1 ->
// dwconv2+silu (row+col layouts) -> 64->34 projection (scan-ordered) ->
// 4-direction selective scan (state-split over 4 waves, atomic partial-y) ->
// double-LN + image-accumulate -> per-pixel mix (cc/sc conv1x1+LN+silu, LN) ->
// MLP 64->256->64 (LDS-staged weights).
// ---------------------------------------------------------------------------

__device__ __forceinline__ float wsum(float v) {
#pragma unroll
  for (int off = 32; off > 0; off >>= 1) v += __shfl_xor(v, off, 64);
  return v;
}
__device__ __forceinline__ float sigm(float x) { return 1.f / (1.f + __expf(-x)); }

// ---- stats: per (b,c) mean of |x2-x1| and 1/(4(v+lam)) -------------------
__global__ __launch_bounds__(256) void k_stats(const float* __restrict__ x1,
                                               const float* __restrict__ x2,
                                               float* __restrict__ meanp,
                                               float* __restrict__ inv4vp) {
  int bc = blockIdx.x;
  const float* p1 = x1 + (size_t)bc * 16384;
  const float* p2 = x2 + (size_t)bc * 16384;
  float s1 = 0.f, s2 = 0.f;
  for (int i = threadIdx.x; i < 16384; i += 256) {
    float d = fabsf(p2[i] - p1[i]);
    s1 += d;
    s2 += d * d;
  }
  s1 = wsum(s1);
  s2 = wsum(s2);
  __shared__ float r1[4], r2[4];
  int wid = threadIdx.x >> 6;
  if ((threadIdx.x & 63) == 0) { r1[wid] = s1; r2[wid] = s2; }
  __syncthreads();
  if (threadIdx.x == 0) {
    float S1 = r1[0] + r1[1] + r1[2] + r1[3];
    float S2 = r2[0] + r2[1] + r2[2] + r2[3];
    float mu = S1 * (1.f / 16384.f);
    float var = (S2 - S1 * mu) * (1.f / 16383.f);
    meanp[bc] = mu;
    inv4vp[bc] = 1.f / (4.f * (var + 1e-4f));
  }
}

// ---- att = sigmoid(g @ dar_w.T + dar_b) ----------------------------------
__global__ void k_att(const float* __restrict__ meanp, const float* __restrict__ dw,
                      const float* __restrict__ db, float* __restrict__ att) {
  int t = threadIdx.x;  // 0..127
  int b = t >> 6, o = t & 63;
  float acc = db[o];
  for (int c = 0; c < 64; c++) acc += meanp[b * 64 + c] * dw[o * 64 + c];
  att[t] = sigm(acc);
}

// ---- prep: x_channels / x_concat in NHWC via LDS transpose ---------------
__global__ __launch_bounds__(256) void k_prep(const float* __restrict__ x1,
                                              const float* __restrict__ x2,
                                              const float* __restrict__ meanp,
                                              const float* __restrict__ inv4vp,
                                              const float* __restrict__ att,
                                              float* __restrict__ xch,
                                              float* __restrict__ xcc) {
  __shared__ float t_ch[64][65], t_cc[64][65];
  int blk = blockIdx.x;
  int b = blk >> 8;
  int p0 = (blk & 255) * 64;
  for (int j = 0; j < 16; j++) {
    int idx = threadIdx.x + j * 256;
    int c = idx >> 6, pp = idx & 63;
    size_t g = ((size_t)(b * 64 + c)) * 16384 + p0 + pp;
    float a = x1[g], bb = x2[g];
    float d = fabsf(bb - a);
    float dm = d - meanp[b * 64 + c];
    float e = dm * dm * inv4vp[b * 64 + c] + 0.5f;
    t_cc[c][pp] = d * sigm(e);
    t_ch[c][pp] = (a + bb) * att[b * 64 + c];
  }
  __syncthreads();
  for (int j = 0; j < 16; j++) {
    int idx = threadIdx.x + j * 256;
    int pp = idx >> 6, c = idx & 63;
    size_t g = ((size_t)(b * 16384 + p0 + pp)) * 64 + c;
    xch[g] = t_ch[c][pp];
    xcc[g] = t_cc[c][pp];
  }
}

// ---- dwconv1: im2cswin gather + depthwise 3x3 (window-SAME) --------------
__global__ __launch_bounds__(256) void k_dwconv1(const float* __restrict__ x1,
                                                 const float* __restrict__ x2,
                                                 const float* __restrict__ w,
                                                 const float* __restrict__ bias,
                                                 float* __restrict__ y1) {
  int blk = blockIdx.x;               // ((i*16+bw)*64+c)
  int c = blk & 63, bw = (blk >> 6) & 15, i = blk >> 10;
  const float* img = (i & 1) ? x2 : x1;
  int lw = (i < 2) ? 4 : 7;
  int SW = 1 << lw;
  int lh = 11 - lw;
  int SH = 1 << lh;
  int b = bw >> 3, r = bw & 7;
  __shared__ float pl[2048];
  const float* ib = img + ((size_t)(b * 64 + c)) * 16384;
  for (int j = threadIdx.x; j < 2048; j += 256) {
    int sh = j >> lw, sw = j & (SW - 1);
    int hh = (i < 2) ? sh : ((sh << 3) + r);
    int ww = (i < 2) ? ((sw << 3) + r) : sw;
    pl[j] = ib[(hh << 7) + ww];
  }
  __syncthreads();
  float w9[9];
#pragma unroll
  for (int t = 0; t < 9; t++) w9[t] = w[(i * 64 + c) * 9 + t];
  float bv = bias[i * 64 + c];
  float* ob = y1 + (size_t)blk * 2048;
  for (int j = threadIdx.x; j < 2048; j += 256) {
    int sh = j >> lw, sw = j & (SW - 1);
    float acc = bv;
#pragma unroll
    for (int dy = 0; dy < 3; dy++) {
      int hh = sh + dy - 1;
      if (hh < 0 || hh >= SH) continue;
#pragma unroll
      for (int dx = 0; dx < 3; dx++) {
        int ww = sw + dx - 1;
        if (ww < 0 || ww >= SW) continue;
        acc += pl[(hh << lw) + ww] * w9[dy * 3 + dx];
      }
    }
    ob[j] = acc;
  }
}

// ---- dwconv2 + silu; writes row-major and col-major copies ---------------
__global__ __launch_bounds__(256) void k_dwconv2(const float* __restrict__ y1,
                                                 const float* __restrict__ w,
                                                 const float* __restrict__ bias,
                                                 float* __restrict__ zr,
                                                 float* __restrict__ zc) {
  int blk = blockIdx.x;
  int c = blk & 63, i = blk >> 10;
  int lw = (i < 2) ? 4 : 7;
  int SW = 1 << lw;
  int lh = 11 - lw;
  int SH = 1 << lh;
  __shared__ float pl[2048];
  __shared__ float zz[2176];  // padded (SW+1) stride
  const float* ibs = y1 + (size_t)blk * 2048;
  for (int j = threadIdx.x; j < 2048; j += 256) pl[j] = ibs[j];
  __syncthreads();
  float w9[9];
#pragma unroll
  for (int t = 0; t < 9; t++) w9[t] = w[(i * 64 + c) * 9 + t];
  float bv = bias[i * 64 + c];
  float* orow = zr + (size_t)blk * 2048;
  for (int j = threadIdx.x; j < 2048; j += 256) {
    int sh = j >> lw, sw = j & (SW - 1);
    float acc = bv;
#pragma unroll
    for (int dy = 0; dy < 3; dy++) {
      int hh = sh + dy - 1;
      if (hh < 0 || hh >= SH) continue;
#pragma unroll
      for (int dx = 0; dx < 3; dx++) {
        int ww = sw + dx - 1;
        if (ww < 0 || ww >= SW) continue;
        acc += pl[(hh << lw) + ww] * w9[dy * 3 + dx];
      }
    }
    float zv = acc * sigm(acc);
    orow[j] = zv;
    zz[sh * (SW + 1) + sw] = zv;
  }
  __syncthreads();
  float* ocol = zc + (size_t)blk * 2048;
  for (int j = threadIdx.x; j < 2048; j += 256) {
    int sh = j & (SH - 1), sw = j >> lh;
    ocol[j] = zz[sh * (SW + 1) + sw];
  }
}

// ---- projection 64 -> 34, written in per-direction scan order ------------
// row layout per l (stride 36): [0..15]=B, [16..31]=C, [32..33]=dt_raw
__global__ __launch_bounds__(256) void k_proj(const float* __restrict__ zr,
                                              const float* __restrict__ zc,
                                              const float* __restrict__ xw,
                                              float* __restrict__ xdbl) {
  int ik = blockIdx.y;
  int i = ik >> 2, k = ik & 3;
  int g = blockIdx.x * 256 + threadIdx.x;
  int bw = g >> 11, l = g & 2047;
  int pos = (k & 2) ? (2047 - l) : l;
  const float* src = ((k & 1) ? zc : zr) + ((size_t)(i * 16 + bw) * 64) * 2048 + pos;
  const float* wp = xw + (size_t)ik * 34 * 64;
  float acc[34];
#pragma unroll
  for (int r = 0; r < 34; r++) acc[r] = 0.f;
  for (int d = 0; d < 64; d++) {
    float zv = src[d << 11];
#pragma unroll
    for (int r = 0; r < 34; r++) acc[r] += zv * wp[r * 64 + d];
  }
  float* o = xdbl + (((size_t)(i * 16 + bw) * 4 + k) * 2048 + l) * 36;
#pragma unroll
  for (int r = 0; r < 34; r++) o[(r < 2) ? (32 + r) : (r - 2)] = acc[r];
}

// ---- selective scan: block=(i,bw) x k, wave = 4-state slice --------------
__global__ __launch_bounds__(256) void k_scan(const float* __restrict__ zr,
                                              const float* __restrict__ zc,
                                              const float* __restrict__ xdbl,
                                              const float* __restrict__ dtw,
                                              const float* __restrict__ dtb_,
                                              const float* __restrict__ alog,
                                              const float* __restrict__ dsp,
                                              float* __restrict__ ysum) {
  int blk = blockIdx.x;  // i*16+bw
  int i = blk >> 4;
  int k = blockIdx.y;
  int ns = threadIdx.x >> 6;
  int d = threadIdx.x & 63;
  int ik = i * 4 + k;
  int lw = (i < 2) ? 4 : 7;
  int lh = 11 - lw;
  int SHm1 = (1 << lh) - 1;
  int bn = ns * 4;
  float A0[4];
#pragma unroll
  for (int j = 0; j < 4; j++) A0[j] = -__expf(alog[((size_t)ik * 64 + d) * 16 + bn + j]);
  float w0 = dtw[((size_t)ik * 64 + d) * 2];
  float w1 = dtw[((size_t)ik * 64 + d) * 2 + 1];
  float bb = dtb_[(size_t)ik * 64 + d];
  float Dv = (ns == 0) ? dsp[(size_t)ik * 64 + d] : 0.f;
  const float* zp = ((k & 1) ? zc : zr) + ((size_t)blk * 64 + d) * 2048;
  const float* xd = xdbl + ((size_t)blk * 4 + k) * 2048 * 36;
  float* yb = ysum + (size_t)blk * 2048 * 64 + d;
  float h0 = 0.f, h1 = 0.f, h2 = 0.f, h3 = 0.f;
  for (int l = 0; l < 2048; l++) {
    const float* row = xd + l * 36;
    float4 Bv = *(const float4*)(row + bn);
    float4 Cv = *(const float4*)(row + 16 + bn);
    float a = row[32] * w0 + row[33] * w1 + bb;
    float dt = fmaxf(a, 0.f) + __logf(1.f + __expf(-fabsf(a)));
    int spos = (k & 2) ? (2047 - l) : l;
    float xv = zp[spos];
    float u = dt * xv;
    float y = Dv * xv;
    h0 = h0 * __expf(dt * A0[0]) + u * Bv.x; y += h0 * Cv.x;
    h1 = h1 * __expf(dt * A0[1]) + u * Bv.y; y += h1 * Cv.y;
    h2 = h2 * __expf(dt * A0[2]) + u * Bv.z; y += h2 * Cv.z;
    h3 = h3 * __expf(dt * A0[3]) + u * Bv.w; y += h3 * Cv.w;
    int sp;
    if (k == 0) sp = l;
    else if (k == 2) sp = 2047 - l;
    else {
      int m = (k == 1) ? l : (2047 - l);
      sp = ((m & SHm1) << lw) | (m >> lh);
    }
    atomicAdd(yb + ((size_t)sp << 6), y);
  }
}

// ---- double channel-LN + accumulate into image-domain branch sum ---------
__global__ __launch_bounds__(256) void k_lnbranch(const float* __restrict__ ysum,
                                                  const float* __restrict__ ng,
                                                  const float* __restrict__ nb,
                                                  const float* __restrict__ bg,
                                                  const float* __restrict__ bbv,
                                                  float* __restrict__ brs) {
  int wid = threadIdx.x >> 6, d = threadIdx.x & 63;
  int gpos = blockIdx.x * 4 + wid;  // ((i*16+bw)*2048+p)
  int p = gpos & 2047, bw = (gpos >> 11) & 15, i = gpos >> 15;
  float v = ysum[(size_t)gpos * 64 + d];
  float mu = wsum(v) * (1.f / 64.f);
  float dv = v - mu;
  float var = wsum(dv * dv) * (1.f / 64.f);
  float t = dv * rsqrtf(var + 1e-6f) * ng[i * 64 + d] + nb[i * 64 + d];
  float mu2 = wsum(t) * (1.f / 64.f);
  float d2 = t - mu2;
  float var2 = wsum(d2 * d2) * (1.f / 64.f);
  float u = d2 * rsqrtf(var2 + 1e-6f) * bg[i * 64 + d] + bbv[i * 64 + d];
  int b = bw >> 3, r = bw & 7;
  int hh, ww;
  if (i < 2) { int sh = p >> 4, sw = p & 15; hh = sh; ww = (sw << 3) + r; }
  else       { int sh = p >> 7, sw = p & 127; hh = (sh << 3) + r; ww = sw; }
  atomicAdd(brs + (((size_t)((b << 14) + (hh << 7) + ww)) << 6) + d, u);
}

// ---- per-pixel: cc/sc conv1x1 + LN + silu, LN -> hfeat -------------------
__global__ __launch_bounds__(256) void k_mixA(
    const float* __restrict__ xch, const float* __restrict__ xcc,
    const float* __restrict__ brs, const float* __restrict__ ccw,
    const float* __restrict__ ccb, const float* __restrict__ cclg,
    const float* __restrict__ cclb, const float* __restrict__ scw,
    const float* __restrict__ scb, const float* __restrict__ sclg,
    const float* __restrict__ sclb, const float* __restrict__ mlg,
    const float* __restrict__ mlb, float* __restrict__ hfeat) {
  __shared__ float sx[4][64], sy[4][64];
  int wid = threadIdx.x >> 6, lane = threadIdx.x & 63;
  int stride = gridDim.x * 4;
  for (int px = blockIdx.x * 4 + wid; px < 32768; px += stride) {
    size_t b64 = (size_t)px * 64;
    float xc = xch[b64 + lane];
    float xs = xcc[b64 + lane] * brs[b64 + lane];
    sx[wid][lane] = xc;
    sy[wid][lane] = xs;
    float a1 = ccb[lane], a2 = scb[lane];
#pragma unroll 4
    for (int c = 0; c < 64; c++) {
      a1 += sx[wid][c] * ccw[lane * 64 + c];
      a2 += sy[wid][c] * scw[lane * 64 + c];
    }
    float m1 = wsum(a1) * (1.f / 64.f);
    float d1 = a1 - m1;
    float v1 = wsum(d1 * d1) * (1.f / 64.f);
    float ch = d1 * rsqrtf(v1 + 1e-6f) * cclg[lane] + cclb[lane];
    ch = ch * sigm(ch);
    float m2 = wsum(a2) * (1.f / 64.f);
    float d2 = a2 - m2;
    float v2 = wsum(d2 * d2) * (1.f / 64.f);
    float sp = d2 * rsqrtf(v2 + 1e-6f) * sclg[lane] + sclb[lane];
    sp = sp * sigm(sp);
    float hs = ch + sp;
    float m3 = wsum(hs) * (1.f / 64.f);
    float d3 = hs - m3;
    float v3 = wsum(d3 * d3) * (1.f / 64.f);
    hfeat[b64 + lane] = d3 * rsqrtf(v3 + 1e-6f) * mlg[lane] + mlb[lane];
  }
}

// ---- MLP 64 -> 256 (silu), weights float4-packed in LDS ------------------
__global__ __launch_bounds__(256) void k_mlp1(const float* __restrict__ hfeat,
                                              const float* __restrict__ w1,
                                              const float* __restrict__ b1,
                                              float* __restrict__ hid) {
  __shared__ float w1p[16384];  // [(c*64+o4)*4+q] = w1[(q*64+o4)*64+c]
  for (int idx = threadIdx.x; idx < 16384; idx += 256) {
    int c = idx >> 8, o4 = (idx >> 2) & 63, q = idx & 3;
    w1p[idx] = w1[((q << 6) + o4) * 64 + c];
  }
  __syncthreads();
  int wid = threadIdx.x >> 6, lane = threadIdx.x & 63;
  float c0 = b1[lane], c1 = b1[64 + lane], c2 = b1[128 + lane], c3 = b1[192 + lane];
  int stride = gridDim.x * 4;
  for (int px = blockIdx.x * 4 + wid; px < 32768; px += stride) {
    float hf = hfeat[(size_t)px * 64 + lane];
    float a0 = c0, a1 = c1, a2 = c2, a3 = c3;
#pragma unroll 4
    for (int c = 0; c < 64; c++) {
      float hv = __shfl(hf, c, 64);
      float4 wv = *(const float4*)&w1p[(c << 8) + (lane << 2)];
      a0 += hv * wv.x;
      a1 += hv * wv.y;
      a2 += hv * wv.z;
      a3 += hv * wv.w;
    }
    size_t ob = (size_t)px * 256;
    hid[ob + lane] = a0 * sigm(a0);
    hid[ob + 64 + lane] = a1 * sigm(a1);
    hid[ob + 128 + lane] = a2 * sigm(a2);
    hid[ob + 192 + lane] = a3 * sigm(a3);
  }
}

// ---- MLP 256 -> 64 + NCHW output write -----------------------------------
__global__ __launch_bounds__(256) void k_mlp2(const float* __restrict__ hid,
                                              const float* __restrict__ w2,
                                              const float* __restrict__ b2,
                                              float* __restrict__ out) {
  __shared__ float w2p[16384];  // [(c4*64+o)*4+j] = w2[o*256+c4*4+j]
  for (int idx = threadIdx.x; idx < 16384; idx += 256) {
    int c4 = idx >> 8, o = (idx >> 2) & 63, j = idx & 3;
    w2p[idx] = w2[o * 256 + (c4 << 2) + j];
  }
  __syncthreads();
  int wid = threadIdx.x >> 6, lane = threadIdx.x & 63;
  float bb = b2[lane];
  int stride = gridDim.x * 4;
  for (int px = blockIdx.x * 4 + wid; px < 32768; px += stride) {
    const float* hp = hid + (size_t)px * 256;
    float acc = bb;
#pragma unroll 4
    for (int c4 = 0; c4 < 64; c4++) {
      float4 hv = *(const float4*)(hp + (c4 << 2));
      float4 wv = *(const float4*)&w2p[(c4 << 8) + (lane << 2)];
      acc += hv.x * wv.x + hv.y * wv.y + hv.z * wv.z + hv.w * wv.w;
    }
    int b = px >> 14, hw = px & 16383;
    out[((size_t)(b * 64 + lane)) * 16384 + hw] = acc;
  }
}

extern "C" void kernel_launch(void* const* d_in, const int* in_sizes, int n_in,
                              void* d_out, int out_size, void* d_ws, size_t ws_size,
                              hipStream_t stream) {
  (void)in_sizes; (void)n_in; (void)out_size;
  const float* x1 = (const float*)d_in[0];
  const float* x2 = (const float*)d_in[1];
  const float* br_dw_w = (const float*)d_in[2];
  const float* br_dw_b = (const float*)d_in[3];
  const float* ss_conv_w = (const float*)d_in[4];
  const float* ss_conv_b = (const float*)d_in[5];
  const float* ss_xproj_w = (const float*)d_in[6];
  const float* ss_dt_w = (const float*)d_in[7];
  const float* ss_dt_b = (const float*)d_in[8];
  const float* ss_Alogs = (const float*)d_in[9];
  const float* ss_Ds = (const float*)d_in[10];
  const float* ss_ng = (const float*)d_in[11];
  const float* ss_nb = (const float*)d_in[12];
  const float* br_ln_g = (const float*)d_in[13];
  const float* br_ln_b = (const float*)d_in[14];
  const float* dar_w = (const float*)d_in[15];
  const float* dar_b = (const float*)d_in[16];
  const float* cc_w = (const float*)d_in[17];
  const float* cc_b = (const float*)d_in[18];
  const float* cc_ln_g = (const float*)d_in[19];
  const float* cc_ln_b = (const float*)d_in[20];
  const float* sc_w = (const float*)d_in[21];
  const float* sc_b = (const float*)d_in[22];
  const float* sc_ln_g = (const float*)d_in[23];
  const float* sc_ln_b = (const float*)d_in[24];
  const float* mlp_ln_g = (const float*)d_in[25];
  const float* mlp_ln_b = (const float*)d_in[26];
  const float* mlp_w1 = (const float*)d_in[27];
  const float* mlp_b1 = (const float*)d_in[28];
  const float* mlp_w2 = (const float*)d_in[29];
  const float* mlp_b2 = (const float*)d_in[30];
  float* out = (float*)d_out;

  // workspace layout (floats); y1/ysum/hfeat share one 32MB region
  // (disjoint lifetimes), mlp hidden aliases x_dbl.
  float* W = (float*)d_ws;
  float* meanp = W;                 // 128
  float* inv4vp = W + 128;          // 128
  float* attp = W + 256;            // 128
  float* xch = W + 1024;            // 2,097,152
  float* xcc = xch + 2097152;       // 2,097,152
  float* brs = xcc + 2097152;       // 2,097,152
  float* sh32 = brs + 2097152;      // 8,388,608 (y1 / ysum / hfeat)
  float* zr = sh32 + 8388608;       // 8,388,608
  float* zc = zr + 8388608;         // 8,388,608
  float* xdbl = zc + 8388608;       // 18,874,368 (also mlp hidden)
  size_t need = (size_t)(1024 + 3 * 2097152 + 3 * 8388608 + 18874368) * sizeof(float);
  if (ws_size < need) return;  // workspace too small; cannot run

  k_stats<<<128, 256, 0, stream>>>(x1, x2, meanp, inv4vp);
  k_att<<<1, 128, 0, stream>>>(meanp, dar_w, dar_b, attp);
  k_prep<<<512, 256, 0, stream>>>(x1, x2, meanp, inv4vp, attp, xch, xcc);
  k_dwconv1<<<4096, 256, 0, stream>>>(x1, x2, br_dw_w, br_dw_b, sh32);
  k_dwconv2<<<4096, 256, 0, stream>>>(sh32, ss_conv_w, ss_conv_b, zr, zc);
  k_proj<<<dim3(128, 16), 256, 0, stream>>>(zr, zc, ss_xproj_w, xdbl);
  hipMemsetAsync(sh32, 0, (size_t)8388608 * sizeof(float), stream);   // ysum = 0
  hipMemsetAsync(brs, 0, (size_t)2097152 * sizeof(float), stream);    // br_sum = 0
  k_scan<<<dim3(64, 4), 256, 0, stream>>>(zr, zc, xdbl, ss_dt_w, ss_dt_b, ss_Alogs,
                                          ss_Ds, sh32);
  k_lnbranch<<<32768, 256, 0, stream>>>(sh32, ss_ng, ss_nb, br_ln_g, br_ln_b, brs);
  k_mixA<<<512, 256, 0, stream>>>(xch, xcc, brs, cc_w, cc_b, cc_ln_g, cc_ln_b, sc_w,
                                  sc_b, sc_ln_g, sc_ln_b, mlp_ln_g, mlp_ln_b, sh32);
  k_mlp1<<<512, 256, 0, stream>>>(sh32, mlp_w1, mlp_b1, xdbl);
  k_mlp2<<<512, 256, 0, stream>>>(xdbl, mlp_w2, mlp_b2, out);
}